// Round 13
// baseline (1030.598 us; speedup 1.0000x reference)
//
#include <hip/hip_runtime.h>

#define BM 64
#define BN 64
#define BK 16
#define PAD 4

typedef double f64x4 __attribute__((ext_vector_type(4)));
typedef int i32x4 __attribute__((ext_vector_type(4)));
typedef int i32x16 __attribute__((ext_vector_type(16)));

// Dense fallback: C[m,h] = sum_d A[m,d] * W[h,d] + bias[h], fp64 accumulation.
template <typename PT>
__global__ __launch_bounds__(256) void gemm_nt(const float* __restrict__ A,
                                               const float* __restrict__ W,
                                               const float* __restrict__ bias,
                                               PT* __restrict__ C,
                                               int M, int D, int H) {
    __shared__ float As[BK][BM + PAD];
    __shared__ float Ws[BK][BN + PAD];
    const int tid = threadIdx.x;
    const int tx = tid & 15;
    const int ty = tid >> 4;
    const int row0 = blockIdx.x * BM;
    const int col0 = blockIdx.y * BN;
    const int lr = tid >> 2;
    const int lk = (tid & 3) << 2;

    double acc[4][4];
#pragma unroll
    for (int i = 0; i < 4; ++i)
#pragma unroll
        for (int j = 0; j < 4; ++j)
            acc[i][j] = (double)bias[col0 + tx * 4 + j];

    const float* Aptr = A + (size_t)(row0 + lr) * D + lk;
    const float* Wptr = W + (size_t)(col0 + lr) * D + lk;

    for (int kk = 0; kk < D; kk += BK) {
        float4 av = *reinterpret_cast<const float4*>(Aptr + kk);
        float4 wv = *reinterpret_cast<const float4*>(Wptr + kk);
        __syncthreads();
        As[lk + 0][lr] = av.x; As[lk + 1][lr] = av.y;
        As[lk + 2][lr] = av.z; As[lk + 3][lr] = av.w;
        Ws[lk + 0][lr] = wv.x; Ws[lk + 1][lr] = wv.y;
        Ws[lk + 2][lr] = wv.z; Ws[lk + 3][lr] = wv.w;
        __syncthreads();
#pragma unroll
        for (int k = 0; k < BK; ++k) {
            float a[4], w[4];
#pragma unroll
            for (int i = 0; i < 4; ++i) a[i] = As[k][ty * 4 + i];
#pragma unroll
            for (int j = 0; j < 4; ++j) w[j] = Ws[k][tx * 4 + j];
#pragma unroll
            for (int i = 0; i < 4; ++i)
#pragma unroll
                for (int j = 0; j < 4; ++j)
                    acc[i][j] += (double)a[i] * (double)w[j];
        }
    }
#pragma unroll
    for (int i = 0; i < 4; ++i) {
        size_t r = (size_t)(row0 + ty * 4 + i) * H + col0 + tx * 4;
#pragma unroll
        for (int j = 0; j < 4; ++j)
            C[r + j] = (PT)acc[i][j];
    }
}

// fp64-MFMA dense GEMM (layer 0): FROZEN R10 config.
__global__ __launch_bounds__(256) void gemm_f64mfma(const float* __restrict__ A,
                                                    const float* __restrict__ W,
                                                    const float* __restrict__ bias,
                                                    double* __restrict__ P,
                                                    int M, int D, int H) {
    __shared__ float As[64][36];
    __shared__ float Bs[64][36];
    const int tid = threadIdx.x;
    const int wave = tid >> 6, lane = tid & 63;
    const int l15 = lane & 15, l4 = lane >> 4;
    const int row0 = blockIdx.x * 64, col0 = blockIdx.y * 64;
    const int lrow = tid >> 2;
    const int lk8 = (tid & 3) << 3;

    // Layout probe: D[i][j] = i; reg r then holds its own row index (proven R8).
    int rowidx[4];
    {
        double pa = (l4 == 0) ? (double)l15 : 0.0;
        double pb = (l4 == 0) ? 1.0 : 0.0;
        f64x4 pd = {0.0, 0.0, 0.0, 0.0};
        pd = __builtin_amdgcn_mfma_f64_16x16x4f64(pa, pb, pd, 0, 0, 0);
#pragma unroll
        for (int i = 0; i < 4; ++i) rowidx[i] = (int)pd[i];
    }

    f64x4 acc[4];
#pragma unroll
    for (int ct = 0; ct < 4; ++ct) {
        double bv = (double)bias[col0 + ct * 16 + l15];
        acc[ct][0] = bv; acc[ct][1] = bv; acc[ct][2] = bv; acc[ct][3] = bv;
    }

    const float* Aptr = A + (size_t)(row0 + lrow) * D + lk8;
    const float* Wptr = W + (size_t)(col0 + lrow) * D + lk8;

    float4 a0 = *reinterpret_cast<const float4*>(Aptr);
    float4 a1 = *reinterpret_cast<const float4*>(Aptr + 4);
    float4 b0 = *reinterpret_cast<const float4*>(Wptr);
    float4 b1 = *reinterpret_cast<const float4*>(Wptr + 4);

    for (int k0 = 0; k0 < D; k0 += 32) {
        __syncthreads();
        *reinterpret_cast<float4*>(&As[lrow][lk8]) = a0;
        *reinterpret_cast<float4*>(&As[lrow][lk8 + 4]) = a1;
        *reinterpret_cast<float4*>(&Bs[lrow][lk8]) = b0;
        *reinterpret_cast<float4*>(&Bs[lrow][lk8 + 4]) = b1;
        __syncthreads();
        if (k0 + 32 < D) {
            a0 = *reinterpret_cast<const float4*>(Aptr + k0 + 32);
            a1 = *reinterpret_cast<const float4*>(Aptr + k0 + 36);
            b0 = *reinterpret_cast<const float4*>(Wptr + k0 + 32);
            b1 = *reinterpret_cast<const float4*>(Wptr + k0 + 36);
        }
#pragma unroll
        for (int ks = 0; ks < 8; ++ks) {
            double a = (double)As[wave * 16 + l15][ks * 4 + l4];
#pragma unroll
            for (int ct = 0; ct < 4; ++ct) {
                double b = (double)Bs[ct * 16 + l15][ks * 4 + l4];
                acc[ct] = __builtin_amdgcn_mfma_f64_16x16x4f64(a, b, acc[ct], 0, 0, 0);
            }
        }
    }
#pragma unroll
    for (int ct = 0; ct < 4; ++ct) {
#pragma unroll
        for (int i = 0; i < 4; ++i) {
            size_t row = (size_t)(row0 + wave * 16 + rowidx[i]);
            P[row * H + col0 + ct * 16 + l15] = acc[ct][i];
        }
    }
}

// Decompose W[h][d] (fp32, exactly j*2^-28, |j| <= 2^23) into 4 signed base-256
// digit planes Wc[c][h][d] (i8): j = d0 + 256*d1 + 65536*d2 + 16777216*d3.
__global__ __launch_bounds__(256) void w_decomp(const float* __restrict__ W,
                                                signed char* __restrict__ Wc) {
    const int i = blockIdx.x * 256 + threadIdx.x;  // 4 elements per thread
    float4 w = reinterpret_cast<const float4*>(W)[i];
    int p0 = 0, p1 = 0, p2 = 0, p3 = 0;
    const float* wp = &w.x;
#pragma unroll
    for (int j = 0; j < 4; ++j) {
        int val = (int)lrintf(wp[j] * 268435456.0f);  // * 2^28, exact
        int d0 = (int)((unsigned)(val + 128) & 255u) - 128;
        int v1 = (val - d0) >> 8;
        int d1 = (int)((unsigned)(v1 + 128) & 255u) - 128;
        int v2 = (v1 - d1) >> 8;
        int d2 = (int)((unsigned)(v2 + 128) & 255u) - 128;
        int d3 = (v2 - d2) >> 8;  // in {-1,0,1}
        p0 |= (d0 & 255) << (8 * j);
        p1 |= (d1 & 255) << (8 * j);
        p2 |= (d2 & 255) << (8 * j);
        p3 |= (d3 & 255) << (8 * j);
    }
    reinterpret_cast<int*>(Wc + 0 * 1048576)[i] = p0;
    reinterpret_cast<int*>(Wc + 1 * 1048576)[i] = p1;
    reinterpret_cast<int*>(Wc + 2 * 1048576)[i] = p2;
    reinterpret_cast<int*>(Wc + 3 * 1048576)[i] = p3;
}

// Convert spike matrix (fp32 0/1) to i8.
__global__ __launch_bounds__(256) void spike_to_i8(const float* __restrict__ S,
                                                   signed char* __restrict__ S8) {
    const int i = blockIdx.x * 256 + threadIdx.x;  // 16 elements per thread
    const float4* p = reinterpret_cast<const float4*>(S + (size_t)i * 16);
    int out[4];
#pragma unroll
    for (int q = 0; q < 4; ++q) {
        float4 v = p[q];
        int b = 0;
        b |= (v.x != 0.0f) ? 1 : 0;
        b |= (v.y != 0.0f) ? (1 << 8) : 0;
        b |= (v.z != 0.0f) ? (1 << 16) : 0;
        b |= (v.w != 0.0f) ? (1 << 24) : 0;
        out[q] = b;
    }
    int4 o = {out[0], out[1], out[2], out[3]};
    reinterpret_cast<int4*>(S8 + (size_t)i * 16)[0] = o;
}

// Exact integer spike GEMM via i8 MFMA: P[m,h] = bias[h] +
//   (C0 + 2^8 C1 + 2^16 C2 + 2^24 C3) * 2^-28, C_c = S8 · Wc[c]^T.
// 64x64 block = 4 waves x (32x32 tile). No LDS: direct L1/L2-cached frag loads.
// A: row=lane&31, k=(lane>>5)*16+elem. B: col=lane&31, k likewise.
// C/D: col=lane&31, row=(reg&3)+8*(reg>>2)+4*(lane>>5) (m74/m101, dtype-indep).
__global__ __launch_bounds__(256, 2) void spike_i8gemm(
    const signed char* __restrict__ S8, const signed char* __restrict__ Wc,
    const float* __restrict__ bias, double* __restrict__ P) {
    const int tid = threadIdx.x;
    const int wave = tid >> 6, lane = tid & 63;
    const int l31 = lane & 31, lg = lane >> 5;
    const int m0 = blockIdx.x * 64 + (wave >> 1) * 32;
    const int h0 = blockIdx.y * 64 + (wave & 1) * 32;

    i32x16 c0 = {0, 0, 0, 0, 0, 0, 0, 0, 0, 0, 0, 0, 0, 0, 0, 0};
    i32x16 c1 = c0, c2 = c0, c3 = c0;

    const signed char* Ap = S8 + (size_t)(m0 + l31) * 1024 + lg * 16;
    const signed char* Bp = Wc + (size_t)(h0 + l31) * 1024 + lg * 16;

    i32x4 a  = *reinterpret_cast<const i32x4*>(Ap);
    i32x4 b0 = *reinterpret_cast<const i32x4*>(Bp);
    i32x4 b1 = *reinterpret_cast<const i32x4*>(Bp + 1048576);
    i32x4 b2 = *reinterpret_cast<const i32x4*>(Bp + 2097152);
    i32x4 b3 = *reinterpret_cast<const i32x4*>(Bp + 3145728);

    for (int k0 = 0; k0 < 1024; k0 += 32) {
        i32x4 an = {0, 0, 0, 0};
        i32x4 bn0 = an, bn1 = an, bn2 = an, bn3 = an;
        if (k0 + 32 < 1024) {
            an  = *reinterpret_cast<const i32x4*>(Ap + k0 + 32);
            bn0 = *reinterpret_cast<const i32x4*>(Bp + k0 + 32);
            bn1 = *reinterpret_cast<const i32x4*>(Bp + 1048576 + k0 + 32);
            bn2 = *reinterpret_cast<const i32x4*>(Bp + 2097152 + k0 + 32);
            bn3 = *reinterpret_cast<const i32x4*>(Bp + 3145728 + k0 + 32);
        }
        c0 = __builtin_amdgcn_mfma_i32_32x32x32_i8(a, b0, c0, 0, 0, 0);
        c1 = __builtin_amdgcn_mfma_i32_32x32x32_i8(a, b1, c1, 0, 0, 0);
        c2 = __builtin_amdgcn_mfma_i32_32x32x32_i8(a, b2, c2, 0, 0, 0);
        c3 = __builtin_amdgcn_mfma_i32_32x32x32_i8(a, b3, c3, 0, 0, 0);
        a = an; b0 = bn0; b1 = bn1; b2 = bn2; b3 = bn3;
    }

    const double bv = (double)bias[h0 + l31];
#pragma unroll
    for (int r = 0; r < 16; ++r) {
        const int row = (r & 3) + 8 * (r >> 2) + 4 * lg;
        double jv = (double)c0[r] + 256.0 * (double)c1[r]
                  + 65536.0 * (double)c2[r] + 16777216.0 * (double)c3[r];
        P[(size_t)(m0 + row) * 1024 + h0 + l31] = bv + jv * 0x1p-28;
    }
}

// 1024x1024 transpose (fallback path only): Wt[d][h] = W[h][d]
__global__ __launch_bounds__(256) void transpose_w(const float* __restrict__ W,
                                                   float* __restrict__ Wt) {
    __shared__ float t[32][33];
    const int N = 1024;
    const int bx = blockIdx.x * 32, by = blockIdx.y * 32;
    int x = bx + threadIdx.x;
    int y = by + threadIdx.y;
#pragma unroll
    for (int j = 0; j < 32; j += 8)
        t[threadIdx.y + j][threadIdx.x] = W[(size_t)(y + j) * N + x];
    __syncthreads();
    x = by + threadIdx.x;
    y = bx + threadIdx.y;
#pragma unroll
    for (int j = 0; j < 32; j += 8)
        Wt[(size_t)(y + j) * N + x] = t[threadIdx.x][threadIdx.y + j];
}

// Sparse spike layer (fallback path only): R8/R10-proven 8-row 4-deep config.
__global__ __launch_bounds__(256, 2) void spike_gemm8p4(const float* __restrict__ S,
                                                        const float* __restrict__ Wt,
                                                        const float* __restrict__ bias,
                                                        double* __restrict__ P) {
    __shared__ int idx[1024];
    __shared__ int cnts[4];
    const int tid = threadIdx.x;
    const int wave = tid >> 6;
    const int lane = tid & 63;
    const int m0 = blockIdx.x * 8;

    int base = 0;
#pragma unroll
    for (int jj = 0; jj < 4; ++jj) {
        const int d = wave * 256 + jj * 64 + lane;
        unsigned mask8 = 0;
#pragma unroll
        for (int r = 0; r < 8; ++r) {
            float s = S[(((size_t)(m0 + r)) << 10) + d];
            mask8 |= (s != 0.0f) ? (1u << r) : 0u;
        }
        unsigned long long b = __ballot(mask8 != 0);
        int pos = __popcll(b & ((1ull << lane) - 1ull));
        if (mask8) idx[wave * 256 + base + pos] = d | (int)(mask8 << 16);
        base += __popcll(b);
    }
    if (lane == 0) {
        int padded = (base + 3) & ~3;
        for (int j = base; j < padded; ++j) idx[wave * 256 + j] = 0;
        cnts[wave] = padded;
    }
    __syncthreads();

    const int h0 = tid * 4;
    double acc[8][4];
    {
        double bv[4];
#pragma unroll
        for (int j = 0; j < 4; ++j) bv[j] = (double)bias[h0 + j];
#pragma unroll
        for (int r = 0; r < 8; ++r)
#pragma unroll
            for (int j = 0; j < 4; ++j) acc[r][j] = bv[j];
    }

#define PROCB(WV, CM)                                                   \
    {                                                                   \
        const unsigned cm_ = (CM);                                      \
        if (cm_) {                                                      \
            const double d0 = (double)(WV).x, d1 = (double)(WV).y,      \
                         d2 = (double)(WV).z, d3 = (double)(WV).w;      \
            _Pragma("unroll")                                           \
            for (int r = 0; r < 8; ++r) {                               \
                if (cm_ & (1u << r)) {                                  \
                    acc[r][0] += d0; acc[r][1] += d1;                   \
                    acc[r][2] += d2; acc[r][3] += d3;                   \
                }                                                       \
            }                                                           \
        }                                                               \
    }

    for (int s = 0; s < 4; ++s) {
        const int cnt = cnts[s];
        if (cnt == 0) continue;
        const int* seg = idx + s * 256;
        unsigned e0 = (unsigned)__builtin_amdgcn_readfirstlane(seg[0]);
        unsigned e1 = (unsigned)__builtin_amdgcn_readfirstlane(seg[1]);
        unsigned e2 = (unsigned)__builtin_amdgcn_readfirstlane(seg[2]);
        unsigned e3 = (unsigned)__builtin_amdgcn_readfirstlane(seg[3]);
        float4 w0 = *reinterpret_cast<const float4*>(Wt + (((size_t)(e0 & 0x3FFu)) << 10) + h0);
        float4 w1 = *reinterpret_cast<const float4*>(Wt + (((size_t)(e1 & 0x3FFu)) << 10) + h0);
        float4 w2 = *reinterpret_cast<const float4*>(Wt + (((size_t)(e2 & 0x3FFu)) << 10) + h0);
        float4 w3 = *reinterpret_cast<const float4*>(Wt + (((size_t)(e3 & 0x3FFu)) << 10) + h0);
        for (int i = 0; i < cnt; i += 4) {
            unsigned n0 = 0, n1 = 0, n2 = 0, n3 = 0;
            float4 x0 = {0, 0, 0, 0}, x1 = {0, 0, 0, 0}, x2 = {0, 0, 0, 0}, x3 = {0, 0, 0, 0};
            if (i + 4 < cnt) {
                n0 = (unsigned)__builtin_amdgcn_readfirstlane(seg[i + 4]);
                n1 = (unsigned)__builtin_amdgcn_readfirstlane(seg[i + 5]);
                n2 = (unsigned)__builtin_amdgcn_readfirstlane(seg[i + 6]);
                n3 = (unsigned)__builtin_amdgcn_readfirstlane(seg[i + 7]);
                x0 = *reinterpret_cast<const float4*>(Wt + (((size_t)(n0 & 0x3FFu)) << 10) + h0);
                x1 = *reinterpret_cast<const float4*>(Wt + (((size_t)(n1 & 0x3FFu)) << 10) + h0);
                x2 = *reinterpret_cast<const float4*>(Wt + (((size_t)(n2 & 0x3FFu)) << 10) + h0);
                x3 = *reinterpret_cast<const float4*>(Wt + (((size_t)(n3 & 0x3FFu)) << 10) + h0);
            }
            PROCB(w0, e0 >> 16);
            PROCB(w1, e1 >> 16);
            PROCB(w2, e2 >> 16);
            PROCB(w3, e3 >> 16);
            e0 = n0; e1 = n1; e2 = n2; e3 = n3;
            w0 = x0; w1 = x1; w2 = x2; w3 = x3;
        }
    }
#undef PROCB

#pragma unroll
    for (int r = 0; r < 8; ++r) {
        double* p = P + (((size_t)(m0 + r)) << 10) + h0;
        p[0] = acc[r][0]; p[1] = acc[r][1]; p[2] = acc[r][2]; p[3] = acc[r][3];
    }
}

// Serial LIF over t for each (b,h) chain.
template <typename PT>
__global__ __launch_bounds__(256) void lif_scan(const PT* __restrict__ P,
                                                float* __restrict__ S,
                                                int B, int T, int H) {
    const int g = blockIdx.x * blockDim.x + threadIdx.x;
    if (g >= B * H) return;
    const int h = g & (H - 1);
    const int b = g / H;
    const size_t base = (size_t)b * T * H + h;
    double u = 0.0;
    for (int t0 = 0; t0 < T; t0 += 8) {
        double I[8];
#pragma unroll
        for (int j = 0; j < 8; ++j)
            I[j] = (double)P[base + (size_t)(t0 + j) * H];
#pragma unroll
        for (int j = 0; j < 8; ++j) {
            u = 0.5 * u + I[j];
            float s;
            if (u >= 0.5) { s = 1.0f; u = 0.0; } else { s = 0.0f; }
            S[base + (size_t)(t0 + j) * H] = s;
        }
    }
}

extern "C" void kernel_launch(void* const* d_in, const int* in_sizes, int n_in,
                              void* d_out, int out_size, void* d_ws, size_t ws_size,
                              hipStream_t stream) {
    const float* x  = (const float*)d_in[0];
    const float* W0 = (const float*)d_in[1];
    const float* b0 = (const float*)d_in[2];
    const float* W1 = (const float*)d_in[3];
    const float* b1 = (const float*)d_in[4];
    const float* W2 = (const float*)d_in[5];
    const float* b2 = (const float*)d_in[6];

    const int B = 32, T = 512, D0 = 512, H = 1024;
    const int M = B * T;  // 16384

    float* S = (float*)d_out;

    dim3 gemm_grid(M / BM, H / BN);
    const int scan_blocks = (B * H) / 256;

    const size_t P_bytes = (size_t)M * H * sizeof(double);        // 128 MB
    const size_t S8_bytes = (size_t)M * H;                        // 16 MB
    const size_t Wc_bytes = (size_t)4 * H * H;                    // 4 MB
    const size_t need_i8 = P_bytes + S8_bytes + Wc_bytes;         // 148 MB
    const size_t need_sparse = P_bytes + (size_t)H * H * 4;       // 132 MB

    if (ws_size >= need_i8) {
        double* P = (double*)d_ws;
        signed char* S8 = (signed char*)d_ws + P_bytes;
        signed char* Wc = (signed char*)d_ws + P_bytes + S8_bytes;
        dim3 i8_grid(M / 64, H / 64);  // 256 x 16

        // Layer 0: dense fp64 MFMA GEMM (frozen R10).
        gemm_f64mfma<<<dim3(M / 64, H / 64), 256, 0, stream>>>(x, W0, b0, P, M, D0, H);
        lif_scan<double><<<scan_blocks, 256, 0, stream>>>(P, S, B, T, H);

        // Layer 1: exact integer i8-MFMA GEMM.
        w_decomp<<<(H * H / 4) / 256, 256, 0, stream>>>(W1, Wc);
        spike_to_i8<<<(M * H / 16) / 256, 256, 0, stream>>>(S, S8);
        spike_i8gemm<<<i8_grid, 256, 0, stream>>>(S8, Wc, b1, P);
        lif_scan<double><<<scan_blocks, 256, 0, stream>>>(P, S, B, T, H);

        // Layer 2: same.
        w_decomp<<<(H * H / 4) / 256, 256, 0, stream>>>(W2, Wc);
        spike_to_i8<<<(M * H / 16) / 256, 256, 0, stream>>>(S, S8);
        spike_i8gemm<<<i8_grid, 256, 0, stream>>>(S8, Wc, b2, P);
        lif_scan<double><<<scan_blocks, 256, 0, stream>>>(P, S, B, T, H);
    } else if (ws_size >= need_sparse) {
        double* P = (double*)d_ws;
        float* Wt = (float*)((char*)d_ws + P_bytes);
        dim3 tgrid(H / 32, H / 32);
        dim3 tblk(32, 8);

        gemm_f64mfma<<<dim3(M / 64, H / 64), 256, 0, stream>>>(x, W0, b0, P, M, D0, H);
        lif_scan<double><<<scan_blocks, 256, 0, stream>>>(P, S, B, T, H);

        transpose_w<<<tgrid, tblk, 0, stream>>>(W1, Wt);
        spike_gemm8p4<<<M / 8, 256, 0, stream>>>(S, Wt, b1, P);
        lif_scan<double><<<scan_blocks, 256, 0, stream>>>(P, S, B, T, H);

        transpose_w<<<tgrid, tblk, 0, stream>>>(W2, Wt);
        spike_gemm8p4<<<M / 8, 256, 0, stream>>>(S, Wt, b2, P);
        lif_scan<double><<<scan_blocks, 256, 0, stream>>>(P, S, B, T, H);
    } else if (ws_size >= P_bytes) {
        double* P = (double*)d_ws;
        gemm_nt<double><<<gemm_grid, 256, 0, stream>>>(x, W0, b0, P, M, D0, H);
        lif_scan<double><<<scan_blocks, 256, 0, stream>>>(P, S, B, T, H);
        gemm_nt<double><<<gemm_grid, 256, 0, stream>>>(S, W1, b1, P, M, H, H);
        lif_scan<double><<<scan_blocks, 256, 0, stream>>>(P, S, B, T, H);
        gemm_nt<double><<<gemm_grid, 256, 0, stream>>>(S, W2, b2, P, M, H, H);
        lif_scan<double><<<scan_blocks, 256, 0, stream>>>(P, S, B, T, H);
    } else {
        float* P = (float*)d_ws;
        gemm_nt<float><<<gemm_grid, 256, 0, stream>>>(x, W0, b0, P, M, D0, H);
        lif_scan<float><<<scan_blocks, 256, 0, stream>>>(P, S, B, T, H);
        gemm_nt<float><<<gemm_grid, 256, 0, stream>>>(S, W1, b1, P, M, H, H);
        lif_scan<float><<<scan_blocks, 256, 0, stream>>>(P, S, B, T, H);
        gemm_nt<float><<<gemm_grid, 256, 0, stream>>>(S, W2, b2, P, M, H, H);
        lif_scan<float><<<scan_blocks, 256, 0, stream>>>(P, S, B, T, H);
    }
}

// Round 14
// 665.473 us; speedup vs baseline: 1.5487x; 1.5487x over previous
//
#include <hip/hip_runtime.h>

#define BM 64
#define BN 64
#define BK 16
#define PAD 4

typedef double f64x4 __attribute__((ext_vector_type(4)));
typedef int i32x4 __attribute__((ext_vector_type(4)));
typedef int i32x16 __attribute__((ext_vector_type(16)));

// Dense fallback: C[m,h] = sum_d A[m,d] * W[h,d] + bias[h], fp64 accumulation.
template <typename PT>
__global__ __launch_bounds__(256) void gemm_nt(const float* __restrict__ A,
                                               const float* __restrict__ W,
                                               const float* __restrict__ bias,
                                               PT* __restrict__ C,
                                               int M, int D, int H) {
    __shared__ float As[BK][BM + PAD];
    __shared__ float Ws[BK][BN + PAD];
    const int tid = threadIdx.x;
    const int tx = tid & 15;
    const int ty = tid >> 4;
    const int row0 = blockIdx.x * BM;
    const int col0 = blockIdx.y * BN;
    const int lr = tid >> 2;
    const int lk = (tid & 3) << 2;

    double acc[4][4];
#pragma unroll
    for (int i = 0; i < 4; ++i)
#pragma unroll
        for (int j = 0; j < 4; ++j)
            acc[i][j] = (double)bias[col0 + tx * 4 + j];

    const float* Aptr = A + (size_t)(row0 + lr) * D + lk;
    const float* Wptr = W + (size_t)(col0 + lr) * D + lk;

    for (int kk = 0; kk < D; kk += BK) {
        float4 av = *reinterpret_cast<const float4*>(Aptr + kk);
        float4 wv = *reinterpret_cast<const float4*>(Wptr + kk);
        __syncthreads();
        As[lk + 0][lr] = av.x; As[lk + 1][lr] = av.y;
        As[lk + 2][lr] = av.z; As[lk + 3][lr] = av.w;
        Ws[lk + 0][lr] = wv.x; Ws[lk + 1][lr] = wv.y;
        Ws[lk + 2][lr] = wv.z; Ws[lk + 3][lr] = wv.w;
        __syncthreads();
#pragma unroll
        for (int k = 0; k < BK; ++k) {
            float a[4], w[4];
#pragma unroll
            for (int i = 0; i < 4; ++i) a[i] = As[k][ty * 4 + i];
#pragma unroll
            for (int j = 0; j < 4; ++j) w[j] = Ws[k][tx * 4 + j];
#pragma unroll
            for (int i = 0; i < 4; ++i)
#pragma unroll
                for (int j = 0; j < 4; ++j)
                    acc[i][j] += (double)a[i] * (double)w[j];
        }
    }
#pragma unroll
    for (int i = 0; i < 4; ++i) {
        size_t r = (size_t)(row0 + ty * 4 + i) * H + col0 + tx * 4;
#pragma unroll
        for (int j = 0; j < 4; ++j)
            C[r + j] = (PT)acc[i][j];
    }
}

// fp64-MFMA dense GEMM (layer 0): FROZEN R10 config.
__global__ __launch_bounds__(256) void gemm_f64mfma(const float* __restrict__ A,
                                                    const float* __restrict__ W,
                                                    const float* __restrict__ bias,
                                                    double* __restrict__ P,
                                                    int M, int D, int H) {
    __shared__ float As[64][36];
    __shared__ float Bs[64][36];
    const int tid = threadIdx.x;
    const int wave = tid >> 6, lane = tid & 63;
    const int l15 = lane & 15, l4 = lane >> 4;
    const int row0 = blockIdx.x * 64, col0 = blockIdx.y * 64;
    const int lrow = tid >> 2;
    const int lk8 = (tid & 3) << 3;

    // Layout probe: D[i][j] = i; reg r then holds its own row index (proven R8).
    int rowidx[4];
    {
        double pa = (l4 == 0) ? (double)l15 : 0.0;
        double pb = (l4 == 0) ? 1.0 : 0.0;
        f64x4 pd = {0.0, 0.0, 0.0, 0.0};
        pd = __builtin_amdgcn_mfma_f64_16x16x4f64(pa, pb, pd, 0, 0, 0);
#pragma unroll
        for (int i = 0; i < 4; ++i) rowidx[i] = (int)pd[i];
    }

    f64x4 acc[4];
#pragma unroll
    for (int ct = 0; ct < 4; ++ct) {
        double bv = (double)bias[col0 + ct * 16 + l15];
        acc[ct][0] = bv; acc[ct][1] = bv; acc[ct][2] = bv; acc[ct][3] = bv;
    }

    const float* Aptr = A + (size_t)(row0 + lrow) * D + lk8;
    const float* Wptr = W + (size_t)(col0 + lrow) * D + lk8;

    float4 a0 = *reinterpret_cast<const float4*>(Aptr);
    float4 a1 = *reinterpret_cast<const float4*>(Aptr + 4);
    float4 b0 = *reinterpret_cast<const float4*>(Wptr);
    float4 b1 = *reinterpret_cast<const float4*>(Wptr + 4);

    for (int k0 = 0; k0 < D; k0 += 32) {
        __syncthreads();
        *reinterpret_cast<float4*>(&As[lrow][lk8]) = a0;
        *reinterpret_cast<float4*>(&As[lrow][lk8 + 4]) = a1;
        *reinterpret_cast<float4*>(&Bs[lrow][lk8]) = b0;
        *reinterpret_cast<float4*>(&Bs[lrow][lk8 + 4]) = b1;
        __syncthreads();
        if (k0 + 32 < D) {
            a0 = *reinterpret_cast<const float4*>(Aptr + k0 + 32);
            a1 = *reinterpret_cast<const float4*>(Aptr + k0 + 36);
            b0 = *reinterpret_cast<const float4*>(Wptr + k0 + 32);
            b1 = *reinterpret_cast<const float4*>(Wptr + k0 + 36);
        }
#pragma unroll
        for (int ks = 0; ks < 8; ++ks) {
            double a = (double)As[wave * 16 + l15][ks * 4 + l4];
#pragma unroll
            for (int ct = 0; ct < 4; ++ct) {
                double b = (double)Bs[ct * 16 + l15][ks * 4 + l4];
                acc[ct] = __builtin_amdgcn_mfma_f64_16x16x4f64(a, b, acc[ct], 0, 0, 0);
            }
        }
    }
#pragma unroll
    for (int ct = 0; ct < 4; ++ct) {
#pragma unroll
        for (int i = 0; i < 4; ++i) {
            size_t row = (size_t)(row0 + wave * 16 + rowidx[i]);
            P[row * H + col0 + ct * 16 + l15] = acc[ct][i];
        }
    }
}

// PACKED fragment layout for i8 MFMA (32x32 subtile = 1024 B = one wave's
// dwordx4 load): subtile (rb,kb) at offset (rb*32+kb)*1024; lane L holds
// row=(L&31), k=(L>>5)*16..+15 at bytes L*16..L*16+15.

// Decompose W[h][d] (fp32, exactly j*2^-28, |j| <= 2^23) into 4 signed base-256
// digit planes in PACKED layout. One wave per subtile (hb,kb).
__global__ __launch_bounds__(256) void w_decomp(const float* __restrict__ W,
                                                signed char* __restrict__ Wc) {
    const int tid = threadIdx.x;
    const int sub = blockIdx.x * 4 + (tid >> 6);  // 0..1023 (32 hb x 32 kb)
    const int lane = tid & 63;
    const int h = (sub >> 5) * 32 + (lane & 31);
    const int k = (sub & 31) * 32 + (lane >> 5) * 16;
    const float* wp = W + (size_t)h * 1024 + k;

    int q0[4] = {0, 0, 0, 0}, q1[4] = {0, 0, 0, 0};
    int q2[4] = {0, 0, 0, 0}, q3[4] = {0, 0, 0, 0};
#pragma unroll
    for (int j = 0; j < 16; ++j) {
        int val = (int)lrintf(wp[j] * 268435456.0f);  // * 2^28, exact
        int d0 = (int)((unsigned)(val + 128) & 255u) - 128;
        int v1 = (val - d0) >> 8;
        int d1 = (int)((unsigned)(v1 + 128) & 255u) - 128;
        int v2 = (v1 - d1) >> 8;
        int d2 = (int)((unsigned)(v2 + 128) & 255u) - 128;
        int d3 = (v2 - d2) >> 8;  // in {-1,0,1}
        q0[j >> 2] |= (d0 & 255) << (8 * (j & 3));
        q1[j >> 2] |= (d1 & 255) << (8 * (j & 3));
        q2[j >> 2] |= (d2 & 255) << (8 * (j & 3));
        q3[j >> 2] |= (d3 & 255) << (8 * (j & 3));
    }
    const size_t off = (size_t)sub * 1024 + lane * 16;
    int4 o0 = {q0[0], q0[1], q0[2], q0[3]};
    int4 o1 = {q1[0], q1[1], q1[2], q1[3]};
    int4 o2 = {q2[0], q2[1], q2[2], q2[3]};
    int4 o3 = {q3[0], q3[1], q3[2], q3[3]};
    *reinterpret_cast<int4*>(Wc + 0 * 1048576 + off) = o0;
    *reinterpret_cast<int4*>(Wc + 1 * 1048576 + off) = o1;
    *reinterpret_cast<int4*>(Wc + 2 * 1048576 + off) = o2;
    *reinterpret_cast<int4*>(Wc + 3 * 1048576 + off) = o3;
}

// Convert spike matrix (fp32 0/1) to i8 in PACKED layout. One wave per
// subtile (mb,kb); lane reads 64B (16 floats) of its row, writes 16B packed.
__global__ __launch_bounds__(256) void spike_to_i8(const float* __restrict__ S,
                                                   signed char* __restrict__ S8) {
    const int tid = threadIdx.x;
    const int sub = blockIdx.x * 4 + (tid >> 6);  // 0..16383 (512 mb x 32 kb)
    const int lane = tid & 63;
    const int m = (sub >> 5) * 32 + (lane & 31);
    const int k = (sub & 31) * 32 + (lane >> 5) * 16;
    const float4* p = reinterpret_cast<const float4*>(S + (size_t)m * 1024 + k);
    int out[4];
#pragma unroll
    for (int q = 0; q < 4; ++q) {
        float4 v = p[q];
        int b = 0;
        b |= (v.x != 0.0f) ? 1 : 0;
        b |= (v.y != 0.0f) ? (1 << 8) : 0;
        b |= (v.z != 0.0f) ? (1 << 16) : 0;
        b |= (v.w != 0.0f) ? (1 << 24) : 0;
        out[q] = b;
    }
    int4 o = {out[0], out[1], out[2], out[3]};
    *reinterpret_cast<int4*>(S8 + (size_t)sub * 1024 + lane * 16) = o;
}

// Exact integer spike GEMM via i8 MFMA on PACKED operands: P[m,h] = bias[h] +
//   (C0 + 2^8 C1 + 2^16 C2 + 2^24 C3) * 2^-28.
// 64x64 block = 4 waves x (32x32 tile). Every fragment load = 1KB contiguous.
// C/D: col=lane&31, row=(reg&3)+8*(reg>>2)+4*(lane>>5) (m74/m101, dtype-indep).
__global__ __launch_bounds__(256, 2) void spike_i8gemm(
    const signed char* __restrict__ S8, const signed char* __restrict__ Wc,
    const float* __restrict__ bias, double* __restrict__ P) {
    const int tid = threadIdx.x;
    const int wave = tid >> 6, lane = tid & 63;
    const int l31 = lane & 31, lg = lane >> 5;
    const int mb = blockIdx.x * 2 + (wave >> 1);
    const int hb = blockIdx.y * 2 + (wave & 1);
    const int m0 = mb * 32, h0 = hb * 32;

    i32x16 c0 = {0, 0, 0, 0, 0, 0, 0, 0, 0, 0, 0, 0, 0, 0, 0, 0};
    i32x16 c1 = c0, c2 = c0, c3 = c0;

    const signed char* Ap = S8 + (size_t)mb * 32768 + lane * 16;   // mb*32 subtiles
    const signed char* Bp = Wc + (size_t)hb * 32768 + lane * 16;   // hb*32 subtiles

    i32x4 a  = *reinterpret_cast<const i32x4*>(Ap);
    i32x4 b0 = *reinterpret_cast<const i32x4*>(Bp);
    i32x4 b1 = *reinterpret_cast<const i32x4*>(Bp + 1048576);
    i32x4 b2 = *reinterpret_cast<const i32x4*>(Bp + 2097152);
    i32x4 b3 = *reinterpret_cast<const i32x4*>(Bp + 3145728);

    for (int kb = 0; kb < 32; ++kb) {
        i32x4 an = {0, 0, 0, 0};
        i32x4 bn0 = an, bn1 = an, bn2 = an, bn3 = an;
        if (kb + 1 < 32) {
            const int off = (kb + 1) * 1024;
            an  = *reinterpret_cast<const i32x4*>(Ap + off);
            bn0 = *reinterpret_cast<const i32x4*>(Bp + off);
            bn1 = *reinterpret_cast<const i32x4*>(Bp + 1048576 + off);
            bn2 = *reinterpret_cast<const i32x4*>(Bp + 2097152 + off);
            bn3 = *reinterpret_cast<const i32x4*>(Bp + 3145728 + off);
        }
        c0 = __builtin_amdgcn_mfma_i32_32x32x32_i8(a, b0, c0, 0, 0, 0);
        c1 = __builtin_amdgcn_mfma_i32_32x32x32_i8(a, b1, c1, 0, 0, 0);
        c2 = __builtin_amdgcn_mfma_i32_32x32x32_i8(a, b2, c2, 0, 0, 0);
        c3 = __builtin_amdgcn_mfma_i32_32x32x32_i8(a, b3, c3, 0, 0, 0);
        a = an; b0 = bn0; b1 = bn1; b2 = bn2; b3 = bn3;
    }

    const double bv = (double)bias[h0 + l31];
#pragma unroll
    for (int r = 0; r < 16; ++r) {
        const int row = (r & 3) + 8 * (r >> 2) + 4 * lg;
        double jv = (double)c0[r] + 256.0 * (double)c1[r]
                  + 65536.0 * (double)c2[r] + 16777216.0 * (double)c3[r];
        P[(size_t)(m0 + row) * 1024 + h0 + l31] = bv + jv * 0x1p-28;
    }
}

// Serial LIF over t for each (b,h) chain.
template <typename PT>
__global__ __launch_bounds__(256) void lif_scan(const PT* __restrict__ P,
                                                float* __restrict__ S,
                                                int B, int T, int H) {
    const int g = blockIdx.x * blockDim.x + threadIdx.x;
    if (g >= B * H) return;
    const int h = g & (H - 1);
    const int b = g / H;
    const size_t base = (size_t)b * T * H + h;
    double u = 0.0;
    for (int t0 = 0; t0 < T; t0 += 8) {
        double I[8];
#pragma unroll
        for (int j = 0; j < 8; ++j)
            I[j] = (double)P[base + (size_t)(t0 + j) * H];
#pragma unroll
        for (int j = 0; j < 8; ++j) {
            u = 0.5 * u + I[j];
            float s;
            if (u >= 0.5) { s = 1.0f; u = 0.0; } else { s = 0.0f; }
            S[base + (size_t)(t0 + j) * H] = s;
        }
    }
}

extern "C" void kernel_launch(void* const* d_in, const int* in_sizes, int n_in,
                              void* d_out, int out_size, void* d_ws, size_t ws_size,
                              hipStream_t stream) {
    const float* x  = (const float*)d_in[0];
    const float* W0 = (const float*)d_in[1];
    const float* b0 = (const float*)d_in[2];
    const float* W1 = (const float*)d_in[3];
    const float* b1 = (const float*)d_in[4];
    const float* W2 = (const float*)d_in[5];
    const float* b2 = (const float*)d_in[6];

    const int B = 32, T = 512, D0 = 512, H = 1024;
    const int M = B * T;  // 16384

    float* S = (float*)d_out;

    dim3 gemm_grid(M / BM, H / BN);
    const int scan_blocks = (B * H) / 256;

    const size_t P_bytes = (size_t)M * H * sizeof(double);        // 128 MB
    const size_t S8_bytes = (size_t)M * H;                        // 16 MB
    const size_t Wc_bytes = (size_t)4 * H * H;                    // 4 MB
    const size_t need_i8 = P_bytes + S8_bytes + Wc_bytes;         // 148 MB
    const size_t P_f_bytes = (size_t)M * H * sizeof(float);

    if (ws_size >= need_i8) {
        double* P = (double*)d_ws;
        signed char* S8 = (signed char*)d_ws + P_bytes;
        signed char* Wc = (signed char*)d_ws + P_bytes + S8_bytes;
        dim3 i8_grid(M / 64, H / 64);  // 256 x 16

        // Layer 0: dense fp64 MFMA GEMM (frozen R10).
        gemm_f64mfma<<<dim3(M / 64, H / 64), 256, 0, stream>>>(x, W0, b0, P, M, D0, H);
        lif_scan<double><<<scan_blocks, 256, 0, stream>>>(P, S, B, T, H);

        // Layer 1: exact integer i8-MFMA GEMM, packed fragment layout.
        w_decomp<<<256, 256, 0, stream>>>(W1, Wc);
        spike_to_i8<<<4096, 256, 0, stream>>>(S, S8);
        spike_i8gemm<<<i8_grid, 256, 0, stream>>>(S8, Wc, b1, P);
        lif_scan<double><<<scan_blocks, 256, 0, stream>>>(P, S, B, T, H);

        // Layer 2: same.
        w_decomp<<<256, 256, 0, stream>>>(W2, Wc);
        spike_to_i8<<<4096, 256, 0, stream>>>(S, S8);
        spike_i8gemm<<<i8_grid, 256, 0, stream>>>(S8, Wc, b2, P);
        lif_scan<double><<<scan_blocks, 256, 0, stream>>>(P, S, B, T, H);
    } else if (ws_size >= P_bytes) {
        double* P = (double*)d_ws;
        gemm_nt<double><<<gemm_grid, 256, 0, stream>>>(x, W0, b0, P, M, D0, H);
        lif_scan<double><<<scan_blocks, 256, 0, stream>>>(P, S, B, T, H);
        gemm_nt<double><<<gemm_grid, 256, 0, stream>>>(S, W1, b1, P, M, H, H);
        lif_scan<double><<<scan_blocks, 256, 0, stream>>>(P, S, B, T, H);
        gemm_nt<double><<<gemm_grid, 256, 0, stream>>>(S, W2, b2, P, M, H, H);
        lif_scan<double><<<scan_blocks, 256, 0, stream>>>(P, S, B, T, H);
    } else if (ws_size >= P_f_bytes) {
        float* P = (float*)d_ws;
        gemm_nt<float><<<gemm_grid, 256, 0, stream>>>(x, W0, b0, P, M, D0, H);
        lif_scan<float><<<scan_blocks, 256, 0, stream>>>(P, S, B, T, H);
        gemm_nt<float><<<gemm_grid, 256, 0, stream>>>(S, W1, b1, P, M, H, H);
        lif_scan<float><<<scan_blocks, 256, 0, stream>>>(P, S, B, T, H);
        gemm_nt<float><<<gemm_grid, 256, 0, stream>>>(S, W2, b2, P, M, H, H);
        lif_scan<float><<<scan_blocks, 256, 0, stream>>>(P, S, B, T, H);
    }
}